// Round 4
// baseline (370.023 us; speedup 1.0000x reference)
//
#include <hip/hip_runtime.h>
#include <hip/hip_bf16.h>
#include <math.h>

#define BATCH      2048
#define IN_DIM     784
#define HIDDEN     512
#define STYLE      128
#define NUM_LABELS 10
#define FC1_STRIDE ((IN_DIM + 1) * HIDDEN)   // 785*512
#define FC2_STRIDE ((HIDDEN + 1) * STYLE)    // 513*128
#define KP1        832                        // IN_DIM padded to mult of 64
#define TB         64
#define BK         64
#define NBLK       512                        // co-residency capacity-guaranteed (see analysis)

// ---- meta (int) layout at d_ws byte 0 ----
#define META_NTILES 31
#define META_TILES  32     // 3 ints per tile: label,pstart,nrows
#define META_PERM   176

// ---- workspace layout (byte offsets) ----
#define XB_OFF   16384ULL                               // [2048][832] bf16
#define W1B_OFF  (XB_OFF  + (size_t)BATCH*KP1*2)        // [10][512][832] bf16 ([L][n][k])
#define W2B_OFF  (W1B_OFF + 10ULL*HIDDEN*KP1*2)         // [10][128][512] bf16 ([L][n][k])
#define H1B_OFF  (W2B_OFF + 10ULL*STYLE*HIDDEN*2)       // [2048][512] bf16 (permuted rows)
#define WS_NEED  (H1B_OFF + (size_t)BATCH*HIDDEN*2)     // ~15.4 MB

#define W1_KB 26
#define W1_NB 16
#define W2_KB 16
#define W2_NB 4
#define W1_TILES (W1_KB*W1_NB*NUM_LABELS)               // 4160
#define W2_TILES (W2_KB*W2_NB*NUM_LABELS)               // 640
#define NT_TOT   (W1_TILES + W2_TILES)
#define XCHUNKS  (BATCH * (KP1/8))                      // 8-col convert units

typedef short short8  __attribute__((ext_vector_type(8)));
typedef float float4e __attribute__((ext_vector_type(4)));

// monotonic grid-barrier tickets; zero-init, never reset (calls serialize on the
// stream, so call c's tickets occupy [c*NBLK,(c+1)*NBLK) -- graph-replay safe)
__device__ int g_bar[2];

__device__ __forceinline__ ushort f2b(float v) {
    __hip_bfloat16 h = __float2bfloat16(v);
    return *reinterpret_cast<ushort*>(&h);
}

__device__ __forceinline__ void grid_sync(int slot) {
    __threadfence();                 // release: our global writes -> device scope
    __syncthreads();
    if (threadIdx.x == 0) {
        int ticket = __hip_atomic_fetch_add(&g_bar[slot], 1, __ATOMIC_ACQ_REL,
                                            __HIP_MEMORY_SCOPE_AGENT);
        int target = (ticket / NBLK + 1) * NBLK;
        while (__hip_atomic_load(&g_bar[slot], __ATOMIC_ACQUIRE,
                                 __HIP_MEMORY_SCOPE_AGENT) < target)
            __builtin_amdgcn_s_sleep(2);
    }
    __syncthreads();
    __threadfence();                 // acquire: invalidate stale cached lines
}

__global__ __launch_bounds__(256, 2)
void k_fused(const float* __restrict__ x, const int* __restrict__ m,
             const float* __restrict__ fc1t, const float* __restrict__ fc2t,
             char* __restrict__ ws, float* __restrict__ out) {
    int*    meta = (int*)ws;
    ushort* xb   = (ushort*)(ws + XB_OFF);
    ushort* w1b  = (ushort*)(ws + W1B_OFF);
    ushort* w2b  = (ushort*)(ws + W2B_OFF);
    ushort* h1b  = (ushort*)(ws + H1B_OFF);

    __shared__ __align__(16) char smem[64*72*2*2 + 256];
    ushort (*As)[72] = (ushort(*)[72])smem;
    ushort (*Bs)[72] = (ushort(*)[72])(smem + 64*72*2);
    int*   rowsS     = (int*)(smem + 64*72*2*2);
    // phase-A overlays (disjoint phases, same storage)
    float (*tileS)[36] = (float(*)[36])smem;    // 4.6 KB
    int* permS = (int*)smem;                    // 8 KB
    int* cntS  = (int*)(smem + 8192);
    int* cursS = (int*)(smem + 8192 + 64);
    int* offsS = (int*)(smem + 8192 + 128);

    const int tid = threadIdx.x, bid = blockIdx.x;

    // ================= Phase A =================
    if (bid == NBLK - 1) {
        // ---- meta: histogram + prefix + scatter + tile table ----
        if (tid < NUM_LABELS) { cntS[tid] = 0; cursS[tid] = 0; }
        __syncthreads();
        for (int b = tid; b < BATCH; b += 256) atomicAdd(&cntS[m[b]], 1);
        __syncthreads();
        if (tid == 0) {
            int off = 0;
            for (int L = 0; L < NUM_LABELS; ++L) { offsS[L] = off; off += cntS[L]; }
            offsS[NUM_LABELS] = off;
        }
        __syncthreads();
        for (int b = tid; b < BATCH; b += 256) {
            int L = m[b];
            int r = atomicAdd(&cursS[L], 1);
            permS[offsS[L] + r] = b;
        }
        __syncthreads();
        for (int i = tid; i < BATCH; i += 256) meta[META_PERM + i] = permS[i];
        if (tid == 0) {
            int idx = 0;
            for (int L = 0; L < NUM_LABELS; ++L) {
                int c = cntS[L], off = offsS[L];
                for (int t = 0; t < c; t += TB) {
                    meta[META_TILES + idx*3 + 0] = L;
                    meta[META_TILES + idx*3 + 1] = off + t;
                    meta[META_TILES + idx*3 + 2] = min(TB, c - t);
                    ++idx;
                }
            }
            meta[META_NTILES] = idx;
        }
    } else {
        // ---- x -> bf16, pad K to 832 (8-col units) ----
        for (int u = bid*256 + tid; u < XCHUNKS; u += (NBLK-1)*256) {
            int row = u / 104, ka = (u - row*104) * 8;
            uint4 o;
            if (ka < IN_DIM) {   // 784 is a multiple of 8: chunks fully valid or fully pad
                float4 p0 = *(const float4*)(x + (size_t)row*IN_DIM + ka);
                float4 p1 = *(const float4*)(x + (size_t)row*IN_DIM + ka + 4);
                ushort t8[8] = {f2b(p0.x), f2b(p0.y), f2b(p0.z), f2b(p0.w),
                                f2b(p1.x), f2b(p1.y), f2b(p1.z), f2b(p1.w)};
                o = *(const uint4*)t8;
            } else o = make_uint4(0u, 0u, 0u, 0u);
            *(uint4*)(xb + (size_t)row*KP1 + ka) = o;
        }
        // ---- weight transpose+convert: dst[L][n][Kpad] = src[L][k][n] ----
        for (int tt = bid; tt < NT_TOT; tt += NBLK - 1) {
            const float* src; ushort* dst; int Kv, Kp, N, kb, nb, L; size_t sL, dL;
            if (tt < W1_TILES) {
                kb = tt % W1_KB; nb = (tt / W1_KB) % W1_NB; L = tt / (W1_KB * W1_NB);
                src = fc1t; dst = w1b; Kv = IN_DIM; Kp = KP1; N = HIDDEN;
                sL = FC1_STRIDE; dL = (size_t)HIDDEN * KP1;
            } else {
                int q = tt - W1_TILES;
                kb = q % W2_KB; nb = (q / W2_KB) % W2_NB; L = q / (W2_KB * W2_NB);
                src = fc2t; dst = w2b; Kv = HIDDEN; Kp = HIDDEN; N = STYLE;
                sL = FC2_STRIDE; dL = (size_t)STYLE * HIDDEN;
            }
            const int k0 = kb*32, n0 = nb*32;
            const int row = tid >> 3, c4 = tid & 7;
            const int gk = k0 + row;
            float4 v = make_float4(0.f, 0.f, 0.f, 0.f);
            if (gk < Kv) v = *(const float4*)(src + (size_t)L*sL + (size_t)gk*N + n0 + c4*4);
            __syncthreads();
            *(float4*)&tileS[row][c4*4] = v;
            __syncthreads();
            const int on = tid >> 3, oc = tid & 7;
            ushort4 o4;
            o4.x = f2b(tileS[oc*4+0][on]); o4.y = f2b(tileS[oc*4+1][on]);
            o4.z = f2b(tileS[oc*4+2][on]); o4.w = f2b(tileS[oc*4+3][on]);
            *(ushort4*)(dst + (size_t)L*dL + (size_t)(n0+on)*Kp + k0 + oc*4) = o4;
        }
    }
    grid_sync(0);

    const int ntiles = meta[META_NTILES];
    const int sr = tid >> 2, sc = tid & 3;
    const int lane = tid & 63, wv = tid >> 6, qd = lane >> 4, ln16 = lane & 15;

    // ================= Phase B: fc1 =================
    for (int j = bid; j < ntiles * 8; j += NBLK) {
        const int t = j >> 3, cb = j & 7;
        const int L      = meta[META_TILES + 3*t + 0];
        const int pstart = meta[META_TILES + 3*t + 1];
        const int nrows  = meta[META_TILES + 3*t + 2];
        const int col0   = cb * 64;
        __syncthreads();
        if (tid < TB) rowsS[tid] = (tid < nrows) ? meta[META_PERM + pstart + tid] : -1;
        __syncthreads();
        const int arow = rowsS[sr];
        const bool aval = (arow >= 0);
        const uint4* __restrict__ agp = (const uint4*)(xb + (size_t)(aval ? arow : 0) * KP1);
        const uint4* __restrict__ bgp = (const uint4*)(w1b + (size_t)L*HIDDEN*KP1 + (size_t)(col0 + sr)*KP1);

        float4e acc[4] = {};
        uint4 a0, a1, b0, b1;
        {
            const int base = sc * 2;
            a0 = aval ? agp[base] : make_uint4(0u,0u,0u,0u);
            a1 = aval ? agp[base+1] : make_uint4(0u,0u,0u,0u);
            b0 = bgp[base]; b1 = bgp[base+1];
        }
        for (int it = 0; it < KP1/BK; ++it) {
            *(uint4*)&As[sr][sc*16 + 0] = a0;
            *(uint4*)&As[sr][sc*16 + 8] = a1;
            *(uint4*)&Bs[sr][sc*16 + 0] = b0;
            *(uint4*)&Bs[sr][sc*16 + 8] = b1;
            __syncthreads();
            if (it + 1 < KP1/BK) {       // prefetch next chunk; overlaps MFMA below
                const int base = (it+1)*8 + sc*2;
                a0 = aval ? agp[base] : make_uint4(0u,0u,0u,0u);
                a1 = aval ? agp[base+1] : make_uint4(0u,0u,0u,0u);
                b0 = bgp[base]; b1 = bgp[base+1];
            }
#pragma unroll
            for (int s = 0; s < 2; ++s) {
                short8 af = *(const short8*)&As[wv*16 + ln16][s*32 + qd*8];
#pragma unroll
                for (int nt = 0; nt < 4; ++nt) {
                    short8 bf = *(const short8*)&Bs[nt*16 + ln16][s*32 + qd*8];
                    acc[nt] = __builtin_amdgcn_mfma_f32_16x16x32_bf16(af, bf, acc[nt], 0, 0, 0);
                }
            }
            __syncthreads();
        }
        const float* __restrict__ bias = fc1t + (size_t)L*FC1_STRIDE + (size_t)IN_DIM*HIDDEN + col0;
#pragma unroll
        for (int nt = 0; nt < 4; ++nt) {
            const int c = nt*16 + ln16;
            const float bs = bias[c];
#pragma unroll
            for (int i = 0; i < 4; ++i) {
                const int r = wv*16 + qd*4 + i;
                if (r < nrows)
                    h1b[(size_t)(pstart + r)*HIDDEN + col0 + c] = f2b(fmaxf(acc[nt][i] + bs, 0.f));
            }
        }
    }
    grid_sync(1);

    // ================= Phase C: fc2 =================
    for (int j = bid; j < ntiles * 2; j += NBLK) {
        const int t = j >> 1, cb = j & 1;
        const int L      = meta[META_TILES + 3*t + 0];
        const int pstart = meta[META_TILES + 3*t + 1];
        const int nrows  = meta[META_TILES + 3*t + 2];
        const int col0   = cb * 64;
        __syncthreads();
        if (tid < TB) rowsS[tid] = (tid < nrows) ? meta[META_PERM + pstart + tid] : -1;
        __syncthreads();
        const bool aval = (sr < nrows);
        const uint4* __restrict__ agp = (const uint4*)(h1b + (size_t)(pstart + (aval ? sr : 0))*HIDDEN);
        const uint4* __restrict__ bgp = (const uint4*)(w2b + (size_t)L*STYLE*HIDDEN + (size_t)(col0 + sr)*HIDDEN);

        float4e acc[4] = {};
        uint4 a0, a1, b0, b1;
        {
            const int base = sc * 2;
            a0 = aval ? agp[base] : make_uint4(0u,0u,0u,0u);
            a1 = aval ? agp[base+1] : make_uint4(0u,0u,0u,0u);
            b0 = bgp[base]; b1 = bgp[base+1];
        }
        for (int it = 0; it < HIDDEN/BK; ++it) {
            *(uint4*)&As[sr][sc*16 + 0] = a0;
            *(uint4*)&As[sr][sc*16 + 8] = a1;
            *(uint4*)&Bs[sr][sc*16 + 0] = b0;
            *(uint4*)&Bs[sr][sc*16 + 8] = b1;
            __syncthreads();
            if (it + 1 < HIDDEN/BK) {
                const int base = (it+1)*8 + sc*2;
                a0 = aval ? agp[base] : make_uint4(0u,0u,0u,0u);
                a1 = aval ? agp[base+1] : make_uint4(0u,0u,0u,0u);
                b0 = bgp[base]; b1 = bgp[base+1];
            }
#pragma unroll
            for (int s = 0; s < 2; ++s) {
                short8 af = *(const short8*)&As[wv*16 + ln16][s*32 + qd*8];
#pragma unroll
                for (int nt = 0; nt < 4; ++nt) {
                    short8 bf = *(const short8*)&Bs[nt*16 + ln16][s*32 + qd*8];
                    acc[nt] = __builtin_amdgcn_mfma_f32_16x16x32_bf16(af, bf, acc[nt], 0, 0, 0);
                }
            }
            __syncthreads();
        }
        const float* __restrict__ bias = fc2t + (size_t)L*FC2_STRIDE + (size_t)HIDDEN*STYLE + col0;
#pragma unroll
        for (int nt = 0; nt < 4; ++nt) {
            const int c = nt*16 + ln16;
            const float bs = bias[c];
#pragma unroll
            for (int i = 0; i < 4; ++i) {
                const int r = wv*16 + qd*4 + i;
                if (r < nrows) {
                    const int orow = rowsS[r];
                    out[(size_t)orow*STYLE + col0 + c] = 1.f / (1.f + __expf(-(acc[nt][i] + bs)));
                }
            }
        }
    }
}

// ---------- fallback (ws too small): fused per-row, slow but correct ----------
__launch_bounds__(256)
__global__ void k_naive(const float* __restrict__ x, const int* __restrict__ m,
                        const float* __restrict__ fc1t, const float* __restrict__ fc2t,
                        float* __restrict__ out) {
    __shared__ float xs[IN_DIM];
    __shared__ float h1[HIDDEN];
    const int b = blockIdx.x, tid = threadIdx.x, L = m[b];
    for (int k = tid; k < IN_DIM; k += 256) xs[k] = x[(size_t)b*IN_DIM + k];
    __syncthreads();
    const float* __restrict__ W1 = fc1t + (size_t)L*FC1_STRIDE;
    for (int j = tid; j < HIDDEN; j += 256) {
        float acc = W1[(size_t)IN_DIM*HIDDEN + j];
        for (int k = 0; k < IN_DIM; ++k) acc = fmaf(xs[k], W1[(size_t)k*HIDDEN + j], acc);
        h1[j] = fmaxf(acc, 0.f);
    }
    __syncthreads();
    const float* __restrict__ W2 = fc2t + (size_t)L*FC2_STRIDE;
    for (int j = tid; j < STYLE; j += 256) {
        float acc = W2[(size_t)HIDDEN*STYLE + j];
        for (int k = 0; k < HIDDEN; ++k) acc = fmaf(h1[k], W2[(size_t)k*STYLE + j], acc);
        out[(size_t)b*STYLE + j] = 1.f / (1.f + __expf(-acc));
    }
}

extern "C" void kernel_launch(void* const* d_in, const int* in_sizes, int n_in,
                              void* d_out, int out_size, void* d_ws, size_t ws_size,
                              hipStream_t stream) {
    const float* x    = (const float*)d_in[0];
    const int*   m    = (const int*)d_in[1];
    const float* fc1t = (const float*)d_in[2];
    const float* fc2t = (const float*)d_in[3];
    float* out = (float*)d_out;

    if (ws_size >= WS_NEED) {
        k_fused<<<NBLK, 256, 0, stream>>>(x, m, fc1t, fc2t, (char*)d_ws, out);
    } else {
        k_naive<<<BATCH, 256, 0, stream>>>(x, m, fc1t, fc2t, out);
    }
}

// Round 5
// 235.847 us; speedup vs baseline: 1.5689x; 1.5689x over previous
//
#include <hip/hip_runtime.h>
#include <hip/hip_bf16.h>
#include <math.h>

#define BATCH      2048
#define IN_DIM     784
#define HIDDEN     512
#define STYLE      128
#define NUM_LABELS 10
#define FC1_STRIDE ((IN_DIM + 1) * HIDDEN)   // 785*512
#define FC2_STRIDE ((HIDDEN + 1) * STYLE)    // 513*128
#define KP1        832                        // IN_DIM padded to mult of 64
#define TB         64
#define BK         64
#define NBLK       512                        // co-residency capacity-guaranteed

// ---- meta (int) layout at d_ws byte 0 ----
#define META_NTILES 31
#define META_TILES  32     // 3 ints per tile: label,pstart,nrows
#define META_PERM   176

// ---- workspace layout (byte offsets) ----
#define XB_OFF   16384ULL                               // [2048][832] bf16
#define W1B_OFF  (XB_OFF  + (size_t)BATCH*KP1*2)        // [10][512][832] bf16 ([L][n][k])
#define W2B_OFF  (W1B_OFF + 10ULL*HIDDEN*KP1*2)         // [10][128][512] bf16 ([L][n][k])
#define H1B_OFF  (W2B_OFF + 10ULL*STYLE*HIDDEN*2)       // [2048][512] bf16 (permuted rows)
#define WS_NEED  (H1B_OFF + (size_t)BATCH*HIDDEN*2)     // ~15.4 MB

#define W1_KB 26
#define W1_NB 16
#define W2_KB 16
#define W2_NB 4
#define W1_TILES (W1_KB*W1_NB*NUM_LABELS)               // 4160
#define W2_TILES (W2_KB*W2_NB*NUM_LABELS)               // 640
#define NT_TOT   (W1_TILES + W2_TILES)
#define XCHUNKS  (BATCH * (KP1/8))                      // 8-col convert units

typedef short short8  __attribute__((ext_vector_type(8)));
typedef float float4e __attribute__((ext_vector_type(4)));

// monotonic grid-barrier tickets; zero-init, never reset (calls serialize on the
// stream, so call c's tickets occupy [c*NBLK,(c+1)*NBLK) -- graph-replay safe)
__device__ int g_bar[2];

__device__ __forceinline__ ushort f2b(float v) {
    __hip_bfloat16 h = __float2bfloat16(v);
    return *reinterpret_cast<ushort*>(&h);
}

// Cooperative-groups-style barrier. KEY (round-4 lesson): spin with RELAXED
// agent-scope loads -- the scope (not the ordering) routes the access past the
// non-coherent XCD L2, so polls see remote progress with NO per-poll
// buffer_inv. ACQUIRE-polling invalidates the XCD L2 every iteration from
// every spinning block and collapses the whole kernel (315us, round 4).
__device__ __forceinline__ void grid_sync(int slot) {
    __syncthreads();                 // drains all waves' stores to L2 (compiler
                                     // emits vmcnt(0) before s_barrier)
    if (threadIdx.x == 0) {
        __threadfence();             // release: one wbl2 flushes XCD L2 -> MALL
        int ticket = __hip_atomic_fetch_add(&g_bar[slot], 1, __ATOMIC_RELAXED,
                                            __HIP_MEMORY_SCOPE_AGENT);
        int target = (ticket / NBLK + 1) * NBLK;
        while (__hip_atomic_load(&g_bar[slot], __ATOMIC_RELAXED,
                                 __HIP_MEMORY_SCOPE_AGENT) < target)
            __builtin_amdgcn_s_sleep(8);
    }
    __syncthreads();
    __threadfence();                 // acquire: invalidate stale L1/L2 once
}

__global__ __launch_bounds__(256, 2)
void k_fused(const float* __restrict__ x, const int* __restrict__ m,
             const float* __restrict__ fc1t, const float* __restrict__ fc2t,
             char* __restrict__ ws, float* __restrict__ out) {
    int*    meta = (int*)ws;
    ushort* xb   = (ushort*)(ws + XB_OFF);
    ushort* w1b  = (ushort*)(ws + W1B_OFF);
    ushort* w2b  = (ushort*)(ws + W2B_OFF);
    ushort* h1b  = (ushort*)(ws + H1B_OFF);

    __shared__ __align__(16) char smem[64*72*2*2 + 256];
    ushort (*As)[72] = (ushort(*)[72])smem;
    ushort (*Bs)[72] = (ushort(*)[72])(smem + 64*72*2);
    int*   rowsS     = (int*)(smem + 64*72*2*2);
    // phase-A overlays (disjoint phases, same storage)
    float (*tileS)[36] = (float(*)[36])smem;    // 4.6 KB
    int* permS = (int*)smem;                    // 8 KB
    int* cntS  = (int*)(smem + 8192);
    int* cursS = (int*)(smem + 8192 + 64);
    int* offsS = (int*)(smem + 8192 + 128);

    const int tid = threadIdx.x, bid = blockIdx.x;

    // ================= Phase A =================
    if (bid == NBLK - 1) {
        // ---- meta: histogram + prefix + scatter + tile table ----
        if (tid < NUM_LABELS) { cntS[tid] = 0; cursS[tid] = 0; }
        __syncthreads();
        for (int b = tid; b < BATCH; b += 256) atomicAdd(&cntS[m[b]], 1);
        __syncthreads();
        if (tid == 0) {
            int off = 0;
            for (int L = 0; L < NUM_LABELS; ++L) { offsS[L] = off; off += cntS[L]; }
            offsS[NUM_LABELS] = off;
        }
        __syncthreads();
        for (int b = tid; b < BATCH; b += 256) {
            int L = m[b];
            int r = atomicAdd(&cursS[L], 1);
            permS[offsS[L] + r] = b;
        }
        __syncthreads();
        for (int i = tid; i < BATCH; i += 256) meta[META_PERM + i] = permS[i];
        if (tid == 0) {
            int idx = 0;
            for (int L = 0; L < NUM_LABELS; ++L) {
                int c = cntS[L], off = offsS[L];
                for (int t = 0; t < c; t += TB) {
                    meta[META_TILES + idx*3 + 0] = L;
                    meta[META_TILES + idx*3 + 1] = off + t;
                    meta[META_TILES + idx*3 + 2] = min(TB, c - t);
                    ++idx;
                }
            }
            meta[META_NTILES] = idx;
        }
    } else {
        // ---- x -> bf16, pad K to 832 (8-col units) ----
        for (int u = bid*256 + tid; u < XCHUNKS; u += (NBLK-1)*256) {
            int row = u / 104, ka = (u - row*104) * 8;
            uint4 o;
            if (ka < IN_DIM) {   // 784 is a multiple of 8: chunks fully valid or fully pad
                float4 p0 = *(const float4*)(x + (size_t)row*IN_DIM + ka);
                float4 p1 = *(const float4*)(x + (size_t)row*IN_DIM + ka + 4);
                ushort t8[8] = {f2b(p0.x), f2b(p0.y), f2b(p0.z), f2b(p0.w),
                                f2b(p1.x), f2b(p1.y), f2b(p1.z), f2b(p1.w)};
                o = *(const uint4*)t8;
            } else o = make_uint4(0u, 0u, 0u, 0u);
            *(uint4*)(xb + (size_t)row*KP1 + ka) = o;
        }
        // ---- weight transpose+convert: dst[L][n][Kpad] = src[L][k][n] ----
        for (int tt = bid; tt < NT_TOT; tt += NBLK - 1) {
            const float* src; ushort* dst; int Kv, Kp, N, kb, nb, L; size_t sL, dL;
            if (tt < W1_TILES) {
                kb = tt % W1_KB; nb = (tt / W1_KB) % W1_NB; L = tt / (W1_KB * W1_NB);
                src = fc1t; dst = w1b; Kv = IN_DIM; Kp = KP1; N = HIDDEN;
                sL = FC1_STRIDE; dL = (size_t)HIDDEN * KP1;
            } else {
                int q = tt - W1_TILES;
                kb = q % W2_KB; nb = (q / W2_KB) % W2_NB; L = q / (W2_KB * W2_NB);
                src = fc2t; dst = w2b; Kv = HIDDEN; Kp = HIDDEN; N = STYLE;
                sL = FC2_STRIDE; dL = (size_t)STYLE * HIDDEN;
            }
            const int k0 = kb*32, n0 = nb*32;
            const int row = tid >> 3, c4 = tid & 7;
            const int gk = k0 + row;
            float4 v = make_float4(0.f, 0.f, 0.f, 0.f);
            if (gk < Kv) v = *(const float4*)(src + (size_t)L*sL + (size_t)gk*N + n0 + c4*4);
            __syncthreads();
            *(float4*)&tileS[row][c4*4] = v;
            __syncthreads();
            const int on = tid >> 3, oc = tid & 7;
            ushort4 o4;
            o4.x = f2b(tileS[oc*4+0][on]); o4.y = f2b(tileS[oc*4+1][on]);
            o4.z = f2b(tileS[oc*4+2][on]); o4.w = f2b(tileS[oc*4+3][on]);
            *(ushort4*)(dst + (size_t)L*dL + (size_t)(n0+on)*Kp + k0 + oc*4) = o4;
        }
    }
    grid_sync(0);

    const int ntiles = meta[META_NTILES];
    const int sr = tid >> 2, sc = tid & 3;
    const int lane = tid & 63, wv = tid >> 6, qd = lane >> 4, ln16 = lane & 15;

    // ================= Phase B: fc1 =================
    for (int j = bid; j < ntiles * 8; j += NBLK) {
        const int t = j >> 3, cb = j & 7;
        const int L      = meta[META_TILES + 3*t + 0];
        const int pstart = meta[META_TILES + 3*t + 1];
        const int nrows  = meta[META_TILES + 3*t + 2];
        const int col0   = cb * 64;
        __syncthreads();
        if (tid < TB) rowsS[tid] = (tid < nrows) ? meta[META_PERM + pstart + tid] : -1;
        __syncthreads();
        const int arow = rowsS[sr];
        const bool aval = (arow >= 0);
        const uint4* __restrict__ agp = (const uint4*)(xb + (size_t)(aval ? arow : 0) * KP1);
        const uint4* __restrict__ bgp = (const uint4*)(w1b + (size_t)L*HIDDEN*KP1 + (size_t)(col0 + sr)*KP1);

        float4e acc[4] = {};
        uint4 a0, a1, b0, b1;
        {
            const int base = sc * 2;
            a0 = aval ? agp[base] : make_uint4(0u,0u,0u,0u);
            a1 = aval ? agp[base+1] : make_uint4(0u,0u,0u,0u);
            b0 = bgp[base]; b1 = bgp[base+1];
        }
        for (int it = 0; it < KP1/BK; ++it) {
            *(uint4*)&As[sr][sc*16 + 0] = a0;
            *(uint4*)&As[sr][sc*16 + 8] = a1;
            *(uint4*)&Bs[sr][sc*16 + 0] = b0;
            *(uint4*)&Bs[sr][sc*16 + 8] = b1;
            __syncthreads();
            if (it + 1 < KP1/BK) {       // prefetch next chunk; overlaps MFMA below
                const int base = (it+1)*8 + sc*2;
                a0 = aval ? agp[base] : make_uint4(0u,0u,0u,0u);
                a1 = aval ? agp[base+1] : make_uint4(0u,0u,0u,0u);
                b0 = bgp[base]; b1 = bgp[base+1];
            }
#pragma unroll
            for (int s = 0; s < 2; ++s) {
                short8 af = *(const short8*)&As[wv*16 + ln16][s*32 + qd*8];
#pragma unroll
                for (int nt = 0; nt < 4; ++nt) {
                    short8 bf = *(const short8*)&Bs[nt*16 + ln16][s*32 + qd*8];
                    acc[nt] = __builtin_amdgcn_mfma_f32_16x16x32_bf16(af, bf, acc[nt], 0, 0, 0);
                }
            }
            __syncthreads();
        }
        const float* __restrict__ bias = fc1t + (size_t)L*FC1_STRIDE + (size_t)IN_DIM*HIDDEN + col0;
#pragma unroll
        for (int nt = 0; nt < 4; ++nt) {
            const int c = nt*16 + ln16;
            const float bs = bias[c];
#pragma unroll
            for (int i = 0; i < 4; ++i) {
                const int r = wv*16 + qd*4 + i;
                if (r < nrows)
                    h1b[(size_t)(pstart + r)*HIDDEN + col0 + c] = f2b(fmaxf(acc[nt][i] + bs, 0.f));
            }
        }
    }
    grid_sync(1);

    // ================= Phase C: fc2 =================
    for (int j = bid; j < ntiles * 2; j += NBLK) {
        const int t = j >> 1, cb = j & 1;
        const int L      = meta[META_TILES + 3*t + 0];
        const int pstart = meta[META_TILES + 3*t + 1];
        const int nrows  = meta[META_TILES + 3*t + 2];
        const int col0   = cb * 64;
        __syncthreads();
        if (tid < TB) rowsS[tid] = (tid < nrows) ? meta[META_PERM + pstart + tid] : -1;
        __syncthreads();
        const bool aval = (sr < nrows);
        const uint4* __restrict__ agp = (const uint4*)(h1b + (size_t)(pstart + (aval ? sr : 0))*HIDDEN);
        const uint4* __restrict__ bgp = (const uint4*)(w2b + (size_t)L*STYLE*HIDDEN + (size_t)(col0 + sr)*HIDDEN);

        float4e acc[4] = {};
        uint4 a0, a1, b0, b1;
        {
            const int base = sc * 2;
            a0 = aval ? agp[base] : make_uint4(0u,0u,0u,0u);
            a1 = aval ? agp[base+1] : make_uint4(0u,0u,0u,0u);
            b0 = bgp[base]; b1 = bgp[base+1];
        }
        for (int it = 0; it < HIDDEN/BK; ++it) {
            *(uint4*)&As[sr][sc*16 + 0] = a0;
            *(uint4*)&As[sr][sc*16 + 8] = a1;
            *(uint4*)&Bs[sr][sc*16 + 0] = b0;
            *(uint4*)&Bs[sr][sc*16 + 8] = b1;
            __syncthreads();
            if (it + 1 < HIDDEN/BK) {
                const int base = (it+1)*8 + sc*2;
                a0 = aval ? agp[base] : make_uint4(0u,0u,0u,0u);
                a1 = aval ? agp[base+1] : make_uint4(0u,0u,0u,0u);
                b0 = bgp[base]; b1 = bgp[base+1];
            }
#pragma unroll
            for (int s = 0; s < 2; ++s) {
                short8 af = *(const short8*)&As[wv*16 + ln16][s*32 + qd*8];
#pragma unroll
                for (int nt = 0; nt < 4; ++nt) {
                    short8 bf = *(const short8*)&Bs[nt*16 + ln16][s*32 + qd*8];
                    acc[nt] = __builtin_amdgcn_mfma_f32_16x16x32_bf16(af, bf, acc[nt], 0, 0, 0);
                }
            }
            __syncthreads();
        }
        const float* __restrict__ bias = fc2t + (size_t)L*FC2_STRIDE + (size_t)HIDDEN*STYLE + col0;
#pragma unroll
        for (int nt = 0; nt < 4; ++nt) {
            const int c = nt*16 + ln16;
            const float bs = bias[c];
#pragma unroll
            for (int i = 0; i < 4; ++i) {
                const int r = wv*16 + qd*4 + i;
                if (r < nrows) {
                    const int orow = rowsS[r];
                    out[(size_t)orow*STYLE + col0 + c] = 1.f / (1.f + __expf(-(acc[nt][i] + bs)));
                }
            }
        }
    }
}

// ---------- fallback (ws too small): fused per-row, slow but correct ----------
__launch_bounds__(256)
__global__ void k_naive(const float* __restrict__ x, const int* __restrict__ m,
                        const float* __restrict__ fc1t, const float* __restrict__ fc2t,
                        float* __restrict__ out) {
    __shared__ float xs[IN_DIM];
    __shared__ float h1[HIDDEN];
    const int b = blockIdx.x, tid = threadIdx.x, L = m[b];
    for (int k = tid; k < IN_DIM; k += 256) xs[k] = x[(size_t)b*IN_DIM + k];
    __syncthreads();
    const float* __restrict__ W1 = fc1t + (size_t)L*FC1_STRIDE;
    for (int j = tid; j < HIDDEN; j += 256) {
        float acc = W1[(size_t)IN_DIM*HIDDEN + j];
        for (int k = 0; k < IN_DIM; ++k) acc = fmaf(xs[k], W1[(size_t)k*HIDDEN + j], acc);
        h1[j] = fmaxf(acc, 0.f);
    }
    __syncthreads();
    const float* __restrict__ W2 = fc2t + (size_t)L*FC2_STRIDE;
    for (int j = tid; j < STYLE; j += 256) {
        float acc = W2[(size_t)HIDDEN*STYLE + j];
        for (int k = 0; k < HIDDEN; ++k) acc = fmaf(h1[k], W2[(size_t)k*STYLE + j], acc);
        out[(size_t)b*STYLE + j] = 1.f / (1.f + __expf(-acc));
    }
}

extern "C" void kernel_launch(void* const* d_in, const int* in_sizes, int n_in,
                              void* d_out, int out_size, void* d_ws, size_t ws_size,
                              hipStream_t stream) {
    const float* x    = (const float*)d_in[0];
    const int*   m    = (const int*)d_in[1];
    const float* fc1t = (const float*)d_in[2];
    const float* fc2t = (const float*)d_in[3];
    float* out = (float*)d_out;

    if (ws_size >= WS_NEED) {
        k_fused<<<NBLK, 256, 0, stream>>>(x, m, fc1t, fc2t, (char*)d_ws, out);
    } else {
        k_naive<<<BATCH, 256, 0, stream>>>(x, m, fc1t, fc2t, out);
    }
}

// Round 6
// 120.738 us; speedup vs baseline: 3.0647x; 1.9534x over previous
//
#include <hip/hip_runtime.h>
#include <hip/hip_bf16.h>
#include <math.h>

#define BATCH      2048
#define IN_DIM     784
#define HIDDEN     512
#define STYLE      128
#define NUM_LABELS 10
#define FC1_STRIDE ((IN_DIM + 1) * HIDDEN)   // 785*512
#define FC2_STRIDE ((HIDDEN + 1) * STYLE)    // 513*128
#define KP1        896                        // IN_DIM padded to mult of 128
#define TB         64
#define BK         128
#define MAX_TILES  48                         // >= max sum(ceil(c_L/64)) = 41

// ---- meta (int) layout at d_ws byte 0 ----
#define META_NTILES 31
#define META_TILES  32     // 3 ints per tile: label,pstart,nrows
#define META_PERM   176

// ---- workspace layout (byte offsets) ----
#define XB_OFF   16384ULL                               // [2048][896] bf16
#define W1B_OFF  (XB_OFF  + (size_t)BATCH*KP1*2)        // [10][512][896] bf16 ([L][n][k])
#define W2B_OFF  (W1B_OFF + 10ULL*HIDDEN*KP1*2)         // [10][128][512] bf16 ([L][n][k])
#define H1B_OFF  (W2B_OFF + 10ULL*STYLE*HIDDEN*2)       // [2048][512] bf16 (permuted rows)
#define WS_NEED  (H1B_OFF + (size_t)BATCH*HIDDEN*2)     // ~15.5 MB

#define W1_KB 28                                        // 896/32
#define W1_NB 16                                        // 512/32
#define W2_KB 16                                        // 512/32
#define W2_NB 4                                         // 128/32
#define W1_TILES (W1_KB*W1_NB*NUM_LABELS)               // 4480
#define W2_TILES (W2_KB*W2_NB*NUM_LABELS)               // 640
#define NT_TOT   (W1_TILES + W2_TILES)                  // 5120
#define XCHUNKS  (BATCH * (KP1/8))                      // 8-short convert units

typedef short short8  __attribute__((ext_vector_type(8)));
typedef float float4e __attribute__((ext_vector_type(4)));

__device__ __forceinline__ ushort f2b(float v) {
    __hip_bfloat16 h = __float2bfloat16(v);
    return *reinterpret_cast<ushort*>(&h);
}

// ---------- prep: block 0 = meta; all blocks share x-convert + W transpose ----------
__global__ void k_prep(const float* __restrict__ x, const int* __restrict__ m,
                       const float* __restrict__ fc1t, const float* __restrict__ fc2t,
                       int* __restrict__ meta, ushort* __restrict__ xb,
                       ushort* __restrict__ w1b, ushort* __restrict__ w2b) {
    const int tid = threadIdx.x, bid = blockIdx.x;
    __shared__ int cnt[NUM_LABELS], curs[NUM_LABELS], offs[NUM_LABELS + 1];
    __shared__ int permS[BATCH];
    __shared__ float tileS[32][36];

    if (bid == 0) {
        // ---- meta: histogram + prefix + scatter + tile table ----
        if (tid < NUM_LABELS) { cnt[tid] = 0; curs[tid] = 0; }
        __syncthreads();
        for (int b = tid; b < BATCH; b += 256) atomicAdd(&cnt[m[b]], 1);
        __syncthreads();
        if (tid == 0) {
            int off = 0;
            for (int L = 0; L < NUM_LABELS; ++L) { offs[L] = off; off += cnt[L]; }
            offs[NUM_LABELS] = off;
        }
        __syncthreads();
        for (int b = tid; b < BATCH; b += 256) {
            int L = m[b];
            int r = atomicAdd(&curs[L], 1);
            permS[offs[L] + r] = b;
        }
        __syncthreads();
        for (int i = tid; i < BATCH; i += 256) meta[META_PERM + i] = permS[i];
        if (tid == 0) {
            int idx = 0;
            for (int L = 0; L < NUM_LABELS; ++L) {
                int c = cnt[L], off = offs[L];
                for (int t = 0; t < c; t += TB) {
                    meta[META_TILES + idx*3 + 0] = L;
                    meta[META_TILES + idx*3 + 1] = off + t;
                    meta[META_TILES + idx*3 + 2] = min(TB, c - t);
                    ++idx;
                }
            }
            meta[META_NTILES] = idx;
        }
        return;
    }

    // ---- x -> bf16, pad K to 896 (8-short units; 784%8==0 so chunks are all-valid or all-pad) ----
    for (int u = (bid - 1)*256 + tid; u < XCHUNKS; u += (NT_TOT)*256) {
        int row = u / (KP1/8), ka = (u - row*(KP1/8)) * 8;
        uint4 o;
        if (ka < IN_DIM) {
            float4 p0 = *(const float4*)(x + (size_t)row*IN_DIM + ka);
            float4 p1 = *(const float4*)(x + (size_t)row*IN_DIM + ka + 4);
            ushort t8[8] = {f2b(p0.x), f2b(p0.y), f2b(p0.z), f2b(p0.w),
                            f2b(p1.x), f2b(p1.y), f2b(p1.z), f2b(p1.w)};
            o = *(const uint4*)t8;
        } else o = make_uint4(0u, 0u, 0u, 0u);
        *(uint4*)(xb + (size_t)row*KP1 + ka) = o;
    }

    // ---- weight transpose+convert: dst[L][n][Kpad] (bf16) = src[L][k][n] (f32); 1 tile/block ----
    {
        const int tt = bid - 1;
        const float* src; ushort* dst; int Kv, Kp, N, kb, nb, L; size_t sL, dL;
        if (tt < W1_TILES) {
            kb = tt % W1_KB; nb = (tt / W1_KB) % W1_NB; L = tt / (W1_KB * W1_NB);
            src = fc1t; dst = w1b; Kv = IN_DIM; Kp = KP1; N = HIDDEN;
            sL = FC1_STRIDE; dL = (size_t)HIDDEN * KP1;
        } else {
            int q = tt - W1_TILES;
            kb = q % W2_KB; nb = (q / W2_KB) % W2_NB; L = q / (W2_KB * W2_NB);
            src = fc2t; dst = w2b; Kv = HIDDEN; Kp = HIDDEN; N = STYLE;
            sL = FC2_STRIDE; dL = (size_t)STYLE * HIDDEN;
        }
        const int k0 = kb*32, n0 = nb*32;
        const int row = tid >> 3, c4 = tid & 7;     // 32 rows x 8 float4-chunks
        const int gk = k0 + row;
        float4 v = make_float4(0.f, 0.f, 0.f, 0.f);
        if (gk < Kv) v = *(const float4*)(src + (size_t)L*sL + (size_t)gk*N + n0 + c4*4);
        *(float4*)&tileS[row][c4*4] = v;
        __syncthreads();
        const int on = tid >> 3, oc = tid & 7;
        ushort4 o4;
        o4.x = f2b(tileS[oc*4+0][on]); o4.y = f2b(tileS[oc*4+1][on]);
        o4.z = f2b(tileS[oc*4+2][on]); o4.w = f2b(tileS[oc*4+3][on]);
        *(ushort4*)(dst + (size_t)L*dL + (size_t)(n0+on)*Kp + k0 + oc*4) = o4;
    }
}

// ---------- fc1: h1b[pstart+i][j] = relu( x[rows[i]]·W1 + b1 ), bf16 MFMA, BK=128 ----------
__launch_bounds__(256, 2)
__global__ void k_fc1m(const ushort* __restrict__ xb, const ushort* __restrict__ w1b,
                       const float* __restrict__ fc1t, const int* __restrict__ meta,
                       ushort* __restrict__ h1b) {
    const int t = blockIdx.x;
    if (t >= meta[META_NTILES]) return;
    const int L      = meta[META_TILES + 3*t + 0];
    const int pstart = meta[META_TILES + 3*t + 1];
    const int nrows  = meta[META_TILES + 3*t + 2];
    const int col0   = blockIdx.y * 64;

    __shared__ int rowsS[TB];
    __shared__ __align__(16) ushort As[64][136];  // [row][k], 272B stride: 16B-aligned, 2-way banks
    __shared__ __align__(16) ushort Bs[64][136];  // [n][k]

    const int tid = threadIdx.x;
    if (tid < TB) rowsS[tid] = (tid < nrows) ? meta[META_PERM + pstart + tid] : -1;
    __syncthreads();

    const int sr = tid >> 2, sc = tid & 3;        // staging: row 0..63, 64B chunk 0..3
    const int lane = tid & 63, wv = tid >> 6, qd = lane >> 4, ln16 = lane & 15;

    const int arow = rowsS[sr];
    const bool aval = (arow >= 0);
    const uint4* __restrict__ agp = (const uint4*)(xb + (size_t)(aval ? arow : 0) * KP1);
    const uint4* __restrict__ bgp = (const uint4*)(w1b + (size_t)L*HIDDEN*KP1 + (size_t)(col0 + sr)*KP1);

    float4e acc[4] = {};
    uint4 a[4], b[4];
#pragma unroll
    for (int j = 0; j < 4; ++j) {
        a[j] = aval ? agp[sc*4 + j] : make_uint4(0u,0u,0u,0u);
        b[j] = bgp[sc*4 + j];
    }
    for (int it = 0; it < KP1/BK; ++it) {
#pragma unroll
        for (int j = 0; j < 4; ++j) {
            *(uint4*)&As[sr][sc*32 + j*8] = a[j];
            *(uint4*)&Bs[sr][sc*32 + j*8] = b[j];
        }
        __syncthreads();
        if (it + 1 < KP1/BK) {        // prefetch next chunk; overlaps the 16 MFMAs
            const int base = (it+1)*16 + sc*4;
#pragma unroll
            for (int j = 0; j < 4; ++j) {
                a[j] = aval ? agp[base + j] : make_uint4(0u,0u,0u,0u);
                b[j] = bgp[base + j];
            }
        }
#pragma unroll
        for (int s = 0; s < 4; ++s) {
            short8 af = *(const short8*)&As[wv*16 + ln16][s*32 + qd*8];
#pragma unroll
            for (int nt = 0; nt < 4; ++nt) {
                short8 bf = *(const short8*)&Bs[nt*16 + ln16][s*32 + qd*8];
                acc[nt] = __builtin_amdgcn_mfma_f32_16x16x32_bf16(af, bf, acc[nt], 0, 0, 0);
            }
        }
        __syncthreads();
    }

    const float* __restrict__ bias = fc1t + (size_t)L*FC1_STRIDE + (size_t)IN_DIM*HIDDEN + col0;
#pragma unroll
    for (int nt = 0; nt < 4; ++nt) {
        const int c = nt*16 + ln16;
        const float bs = bias[c];
#pragma unroll
        for (int i = 0; i < 4; ++i) {
            const int r = wv*16 + qd*4 + i;
            if (r < nrows)
                h1b[(size_t)(pstart + r)*HIDDEN + col0 + c] = f2b(fmaxf(acc[nt][i] + bs, 0.f));
        }
    }
}

// ---------- fc2: out[rows[i]][j] = sigmoid( h1[i]·W2 + b2 ), bf16 MFMA, BK=128 ----------
__launch_bounds__(256, 2)
__global__ void k_fc2m(const ushort* __restrict__ h1b, const ushort* __restrict__ w2b,
                       const float* __restrict__ fc2t, const int* __restrict__ meta,
                       float* __restrict__ out) {
    const int t = blockIdx.x;
    if (t >= meta[META_NTILES]) return;
    const int L      = meta[META_TILES + 3*t + 0];
    const int pstart = meta[META_TILES + 3*t + 1];
    const int nrows  = meta[META_TILES + 3*t + 2];
    const int col0   = blockIdx.y * 64;

    __shared__ int rowsS[TB];
    __shared__ __align__(16) ushort As[64][136];
    __shared__ __align__(16) ushort Bs[64][136];

    const int tid = threadIdx.x;
    if (tid < TB) rowsS[tid] = (tid < nrows) ? meta[META_PERM + pstart + tid] : -1;
    __syncthreads();

    const int sr = tid >> 2, sc = tid & 3;
    const int lane = tid & 63, wv = tid >> 6, qd = lane >> 4, ln16 = lane & 15;

    const bool aval = (sr < nrows);
    const uint4* __restrict__ agp = (const uint4*)(h1b + (size_t)(pstart + (aval ? sr : 0))*HIDDEN);
    const uint4* __restrict__ bgp = (const uint4*)(w2b + (size_t)L*STYLE*HIDDEN + (size_t)(col0 + sr)*HIDDEN);

    float4e acc[4] = {};
    uint4 a[4], b[4];
#pragma unroll
    for (int j = 0; j < 4; ++j) {
        a[j] = aval ? agp[sc*4 + j] : make_uint4(0u,0u,0u,0u);
        b[j] = bgp[sc*4 + j];
    }
    for (int it = 0; it < HIDDEN/BK; ++it) {
#pragma unroll
        for (int j = 0; j < 4; ++j) {
            *(uint4*)&As[sr][sc*32 + j*8] = a[j];
            *(uint4*)&Bs[sr][sc*32 + j*8] = b[j];
        }
        __syncthreads();
        if (it + 1 < HIDDEN/BK) {
            const int base = (it+1)*16 + sc*4;
#pragma unroll
            for (int j = 0; j < 4; ++j) {
                a[j] = aval ? agp[base + j] : make_uint4(0u,0u,0u,0u);
                b[j] = bgp[base + j];
            }
        }
#pragma unroll
        for (int s = 0; s < 4; ++s) {
            short8 af = *(const short8*)&As[wv*16 + ln16][s*32 + qd*8];
#pragma unroll
            for (int nt = 0; nt < 4; ++nt) {
                short8 bf = *(const short8*)&Bs[nt*16 + ln16][s*32 + qd*8];
                acc[nt] = __builtin_amdgcn_mfma_f32_16x16x32_bf16(af, bf, acc[nt], 0, 0, 0);
            }
        }
        __syncthreads();
    }

    const float* __restrict__ bias = fc2t + (size_t)L*FC2_STRIDE + (size_t)HIDDEN*STYLE + col0;
#pragma unroll
    for (int nt = 0; nt < 4; ++nt) {
        const int c = nt*16 + ln16;
        const float bs = bias[c];
#pragma unroll
        for (int i = 0; i < 4; ++i) {
            const int r = wv*16 + qd*4 + i;
            if (r < nrows) {
                const int orow = rowsS[r];
                out[(size_t)orow*STYLE + col0 + c] = 1.f / (1.f + __expf(-(acc[nt][i] + bs)));
            }
        }
    }
}

// ---------- fallback (ws too small): fused per-row, slow but correct ----------
__launch_bounds__(256)
__global__ void k_naive(const float* __restrict__ x, const int* __restrict__ m,
                        const float* __restrict__ fc1t, const float* __restrict__ fc2t,
                        float* __restrict__ out) {
    __shared__ float xs[IN_DIM];
    __shared__ float h1[HIDDEN];
    const int b = blockIdx.x, tid = threadIdx.x, L = m[b];
    for (int k = tid; k < IN_DIM; k += 256) xs[k] = x[(size_t)b*IN_DIM + k];
    __syncthreads();
    const float* __restrict__ W1 = fc1t + (size_t)L*FC1_STRIDE;
    for (int j = tid; j < HIDDEN; j += 256) {
        float acc = W1[(size_t)IN_DIM*HIDDEN + j];
        for (int k = 0; k < IN_DIM; ++k) acc = fmaf(xs[k], W1[(size_t)k*HIDDEN + j], acc);
        h1[j] = fmaxf(acc, 0.f);
    }
    __syncthreads();
    const float* __restrict__ W2 = fc2t + (size_t)L*FC2_STRIDE;
    for (int j = tid; j < STYLE; j += 256) {
        float acc = W2[(size_t)HIDDEN*STYLE + j];
        for (int k = 0; k < HIDDEN; ++k) acc = fmaf(h1[k], W2[(size_t)k*STYLE + j], acc);
        out[(size_t)b*STYLE + j] = 1.f / (1.f + __expf(-acc));
    }
}

extern "C" void kernel_launch(void* const* d_in, const int* in_sizes, int n_in,
                              void* d_out, int out_size, void* d_ws, size_t ws_size,
                              hipStream_t stream) {
    const float* x    = (const float*)d_in[0];
    const int*   m    = (const int*)d_in[1];
    const float* fc1t = (const float*)d_in[2];
    const float* fc2t = (const float*)d_in[3];
    float* out = (float*)d_out;

    if (ws_size >= WS_NEED) {
        int*    meta = (int*)d_ws;
        ushort* xb   = (ushort*)((char*)d_ws + XB_OFF);
        ushort* w1b  = (ushort*)((char*)d_ws + W1B_OFF);
        ushort* w2b  = (ushort*)((char*)d_ws + W2B_OFF);
        ushort* h1b  = (ushort*)((char*)d_ws + H1B_OFF);

        k_prep<<<1 + NT_TOT, 256, 0, stream>>>(x, m, fc1t, fc2t, meta, xb, w1b, w2b);
        k_fc1m<<<dim3(MAX_TILES, HIDDEN / 64), 256, 0, stream>>>(xb, w1b, fc1t, meta, h1b);
        k_fc2m<<<dim3(MAX_TILES, STYLE / 64), 256, 0, stream>>>(h1b, w2b, fc2t, meta, out);
    } else {
        k_naive<<<BATCH, 256, 0, stream>>>(x, m, fc1t, fc2t, out);
    }
}

// Round 7
// 103.312 us; speedup vs baseline: 3.5816x; 1.1687x over previous
//
#include <hip/hip_runtime.h>
#include <hip/hip_bf16.h>
#include <math.h>

#define BATCH      2048
#define IN_DIM     784
#define HIDDEN     512
#define STYLE      128
#define NUM_LABELS 10
#define FC1_STRIDE ((IN_DIM + 1) * HIDDEN)   // 785*512
#define FC2_STRIDE ((HIDDEN + 1) * STYLE)    // 513*128
#define KP1        832                        // IN_DIM padded to mult of 64
#define TB         64
#define BK         64
#define MAX_TILES  48    // >= max possible sum(ceil(c_L/64)) = 41

// ---- meta (int) layout at d_ws byte 0 ----
#define META_NTILES 31
#define META_TILES  32     // 3 ints per tile: label,pstart,nrows
#define META_PERM   176

// ---- bf16 workspace layout (byte offsets) ----
#define W1B_OFF  16384ULL                               // [10][512][832] bf16 ([L][n][k])
#define W2B_OFF  (W1B_OFF + 10ULL*HIDDEN*KP1*2)         // [10][128][512] bf16 ([L][n][k])
#define H1B_OFF  (W2B_OFF + 10ULL*STYLE*HIDDEN*2)       // [2048][512] bf16 (permuted rows)
#define BF16_NEED (H1B_OFF + (size_t)BATCH*HIDDEN*2)    // ~11.9 MB

#define W1_KB 26                                        // 832/32
#define W1_NB 16                                        // 512/32
#define W2_KB 16                                        // 512/32
#define W2_NB 4                                         // 128/32
#define W1_BLOCKS (W1_KB*W1_NB*NUM_LABELS)              // 4160
#define W2_BLOCKS (W2_KB*W2_NB*NUM_LABELS)              // 640

typedef short short8  __attribute__((ext_vector_type(8)));
typedef float float4e __attribute__((ext_vector_type(4)));

__device__ __forceinline__ ushort f2b(float v) {
    __hip_bfloat16 h = __float2bfloat16(v);
    return *reinterpret_cast<ushort*>(&h);
}

// ---------- prep: block 0 = meta; rest = weight transpose+convert (round-3 exact) ----------
__global__ void k_prep(const int* __restrict__ m, const float* __restrict__ fc1t,
                       const float* __restrict__ fc2t, int* __restrict__ meta,
                       ushort* __restrict__ w1b, ushort* __restrict__ w2b) {
    const int tid = threadIdx.x;
    int bid = blockIdx.x;

    __shared__ int cnt[NUM_LABELS], curs[NUM_LABELS], offs[NUM_LABELS + 1];
    __shared__ int permS[BATCH];
    __shared__ float tile[32][33];

    if (bid == 0) {
        if (tid < NUM_LABELS) { cnt[tid] = 0; curs[tid] = 0; }
        __syncthreads();
        for (int b = tid; b < BATCH; b += 256) atomicAdd(&cnt[m[b]], 1);
        __syncthreads();
        if (tid == 0) {
            int off = 0;
            for (int L = 0; L < NUM_LABELS; ++L) { offs[L] = off; off += cnt[L]; }
            offs[NUM_LABELS] = off;
        }
        __syncthreads();
        for (int b = tid; b < BATCH; b += 256) {
            int L = m[b];
            int r = atomicAdd(&curs[L], 1);
            permS[offs[L] + r] = b;
        }
        __syncthreads();
        for (int i = tid; i < BATCH; i += 256) meta[META_PERM + i] = permS[i];
        if (tid == 0) {
            int idx = 0;
            for (int L = 0; L < NUM_LABELS; ++L) {
                int c = cnt[L], off = offs[L];
                for (int t = 0; t < c; t += TB) {
                    meta[META_TILES + idx * 3 + 0] = L;
                    meta[META_TILES + idx * 3 + 1] = off + t;
                    meta[META_TILES + idx * 3 + 2] = min(TB, c - t);
                    ++idx;
                }
            }
            meta[META_NTILES] = idx;
        }
        return;
    }

    bid -= 1;
    const float* src; ushort* dst; int Kvalid, Kpad, N, kb, nb, L; size_t srcL, dstL;
    if (bid < W1_BLOCKS) {
        kb = bid % W1_KB; nb = (bid / W1_KB) % W1_NB; L = bid / (W1_KB * W1_NB);
        src = fc1t; dst = w1b; Kvalid = IN_DIM; Kpad = KP1; N = HIDDEN;
        srcL = FC1_STRIDE; dstL = (size_t)HIDDEN * KP1;
    } else {
        bid -= W1_BLOCKS;
        kb = bid % W2_KB; nb = (bid / W2_KB) % W2_NB; L = bid / (W2_KB * W2_NB);
        src = fc2t; dst = w2b; Kvalid = HIDDEN; Kpad = HIDDEN; N = STYLE;
        srcL = FC2_STRIDE; dstL = (size_t)STYLE * HIDDEN;
    }
    const int tx = tid & 31, ty = tid >> 5;
    const int k0 = kb * 32, n0 = nb * 32;
    for (int r = ty; r < 32; r += 8) {
        int k = k0 + r;
        tile[r][tx] = (k < Kvalid) ? src[(size_t)L * srcL + (size_t)k * N + n0 + tx] : 0.f;
    }
    __syncthreads();
    for (int r = ty; r < 32; r += 8) {
        int n = n0 + r;
        dst[(size_t)L * dstL + (size_t)n * Kpad + k0 + tx] = f2b(tile[tx][r]);
    }
}

// ---------- fc1: bf16 MFMA, BK=64, + register prefetch (the ONE change vs round 3) ----------
__launch_bounds__(256)
__global__ void k_fc1m(const float* __restrict__ x, const ushort* __restrict__ w1b,
                       const float* __restrict__ fc1t, const int* __restrict__ meta,
                       ushort* __restrict__ h1b) {
    const int t = blockIdx.x;
    if (t >= meta[META_NTILES]) return;
    const int L      = meta[META_TILES + 3 * t + 0];
    const int pstart = meta[META_TILES + 3 * t + 1];
    const int nrows  = meta[META_TILES + 3 * t + 2];
    const int col0   = blockIdx.y * 64;
    const ushort* __restrict__ W = w1b + (size_t)L * HIDDEN * KP1 + (size_t)col0 * KP1;

    __shared__ int rows[TB];
    __shared__ __align__(16) ushort As[64][72];
    __shared__ __align__(16) ushort Bs[64][72];

    const int tid = threadIdx.x;
    if (tid < TB) rows[tid] = (tid < nrows) ? meta[META_PERM + pstart + tid] : -1;
    __syncthreads();

    const int sr = tid >> 2, sc = tid & 3;
    const int lane = tid & 63, wv = tid >> 6;
    const int qd = lane >> 4, ln16 = lane & 15;

    const int arow = rows[sr];
    const float* __restrict__ xr = x + (size_t)(arow < 0 ? 0 : arow) * IN_DIM;
    const uint4* __restrict__ bgp = (const uint4*)(W + (size_t)sr * KP1);

    float4e acc[4] = {};

    // prefetch iteration 0
    float4 a0 = make_float4(0.f,0.f,0.f,0.f), a1 = a0, a2 = a0, a3 = a0;
    uint4 b0, b1;
    {
        const int ka = sc * 16;
        if (arow >= 0) {
            if (ka      < IN_DIM) a0 = *(const float4*)(xr + ka);
            if (ka + 4  < IN_DIM) a1 = *(const float4*)(xr + ka + 4);
            if (ka + 8  < IN_DIM) a2 = *(const float4*)(xr + ka + 8);
            if (ka + 12 < IN_DIM) a3 = *(const float4*)(xr + ka + 12);
        }
        b0 = bgp[sc * 2 + 0];
        b1 = bgp[sc * 2 + 1];
    }

    for (int k0 = 0; k0 < KP1; k0 += BK) {
        ushort av[16];
        av[0]=f2b(a0.x); av[1]=f2b(a0.y); av[2]=f2b(a0.z); av[3]=f2b(a0.w);
        av[4]=f2b(a1.x); av[5]=f2b(a1.y); av[6]=f2b(a1.z); av[7]=f2b(a1.w);
        av[8]=f2b(a2.x); av[9]=f2b(a2.y); av[10]=f2b(a2.z); av[11]=f2b(a2.w);
        av[12]=f2b(a3.x); av[13]=f2b(a3.y); av[14]=f2b(a3.z); av[15]=f2b(a3.w);
        *(uint4*)&As[sr][sc * 16 + 0] = *(const uint4*)&av[0];
        *(uint4*)&As[sr][sc * 16 + 8] = *(const uint4*)&av[8];
        *(uint4*)&Bs[sr][sc * 16 + 0] = b0;
        *(uint4*)&Bs[sr][sc * 16 + 8] = b1;
        __syncthreads();

        if (k0 + BK < KP1) {        // prefetch next chunk; loads fly under the MFMAs
            const int ka = k0 + BK + sc * 16;
            a0 = make_float4(0.f,0.f,0.f,0.f); a1 = a0; a2 = a0; a3 = a0;
            if (arow >= 0) {
                if (ka      < IN_DIM) a0 = *(const float4*)(xr + ka);
                if (ka + 4  < IN_DIM) a1 = *(const float4*)(xr + ka + 4);
                if (ka + 8  < IN_DIM) a2 = *(const float4*)(xr + ka + 8);
                if (ka + 12 < IN_DIM) a3 = *(const float4*)(xr + ka + 12);
            }
            b0 = bgp[((k0 + BK) >> 3) + sc * 2 + 0];
            b1 = bgp[((k0 + BK) >> 3) + sc * 2 + 1];
        }

#pragma unroll
        for (int s = 0; s < 2; ++s) {
            short8 af = *(const short8*)&As[wv * 16 + ln16][s * 32 + qd * 8];
#pragma unroll
            for (int nt = 0; nt < 4; ++nt) {
                short8 bf = *(const short8*)&Bs[nt * 16 + ln16][s * 32 + qd * 8];
                acc[nt] = __builtin_amdgcn_mfma_f32_16x16x32_bf16(af, bf, acc[nt], 0, 0, 0);
            }
        }
        __syncthreads();
    }

    const float* __restrict__ bias = fc1t + (size_t)L * FC1_STRIDE + (size_t)IN_DIM * HIDDEN + col0;
#pragma unroll
    for (int nt = 0; nt < 4; ++nt) {
        const int c = nt * 16 + ln16;
        const float bs = bias[c];
#pragma unroll
        for (int i = 0; i < 4; ++i) {
            const int r = wv * 16 + qd * 4 + i;
            if (r < nrows)
                h1b[(size_t)(pstart + r) * HIDDEN + col0 + c] = f2b(fmaxf(acc[nt][i] + bs, 0.f));
        }
    }
}

// ---------- fc2: bf16 MFMA, BK=64, + register prefetch ----------
__launch_bounds__(256)
__global__ void k_fc2m(const ushort* __restrict__ h1b, const ushort* __restrict__ w2b,
                       const float* __restrict__ fc2t, const int* __restrict__ meta,
                       float* __restrict__ out) {
    const int t = blockIdx.x;
    if (t >= meta[META_NTILES]) return;
    const int L      = meta[META_TILES + 3 * t + 0];
    const int pstart = meta[META_TILES + 3 * t + 1];
    const int nrows  = meta[META_TILES + 3 * t + 2];
    const int col0   = blockIdx.y * 64;
    const ushort* __restrict__ W = w2b + (size_t)L * STYLE * HIDDEN + (size_t)col0 * HIDDEN;

    __shared__ int rows[TB];
    __shared__ __align__(16) ushort As[64][72];
    __shared__ __align__(16) ushort Bs[64][72];

    const int tid = threadIdx.x;
    if (tid < TB) rows[tid] = (tid < nrows) ? meta[META_PERM + pstart + tid] : -1;
    __syncthreads();

    const int sr = tid >> 2, sc = tid & 3;
    const int lane = tid & 63, wv = tid >> 6;
    const int qd = lane >> 4, ln16 = lane & 15;

    const bool aval = (sr < nrows);
    const uint4* __restrict__ agp = (const uint4*)(h1b + (size_t)(pstart + (aval ? sr : 0)) * HIDDEN);
    const uint4* __restrict__ bgp = (const uint4*)(W + (size_t)sr * HIDDEN);

    float4e acc[4] = {};

    uint4 a0 = make_uint4(0u,0u,0u,0u), a1 = a0, b0, b1;
    if (aval) { a0 = agp[sc * 2 + 0]; a1 = agp[sc * 2 + 1]; }
    b0 = bgp[sc * 2 + 0];
    b1 = bgp[sc * 2 + 1];

    for (int k0 = 0; k0 < HIDDEN; k0 += BK) {
        *(uint4*)&As[sr][sc * 16 + 0] = a0;
        *(uint4*)&As[sr][sc * 16 + 8] = a1;
        *(uint4*)&Bs[sr][sc * 16 + 0] = b0;
        *(uint4*)&Bs[sr][sc * 16 + 8] = b1;
        __syncthreads();

        if (k0 + BK < HIDDEN) {
            const int base = ((k0 + BK) >> 3) + sc * 2;
            a0 = make_uint4(0u,0u,0u,0u); a1 = a0;
            if (aval) { a0 = agp[base]; a1 = agp[base + 1]; }
            b0 = bgp[base];
            b1 = bgp[base + 1];
        }

#pragma unroll
        for (int s = 0; s < 2; ++s) {
            short8 af = *(const short8*)&As[wv * 16 + ln16][s * 32 + qd * 8];
#pragma unroll
            for (int nt = 0; nt < 4; ++nt) {
                short8 bf = *(const short8*)&Bs[nt * 16 + ln16][s * 32 + qd * 8];
                acc[nt] = __builtin_amdgcn_mfma_f32_16x16x32_bf16(af, bf, acc[nt], 0, 0, 0);
            }
        }
        __syncthreads();
    }

    const float* __restrict__ bias = fc2t + (size_t)L * FC2_STRIDE + (size_t)HIDDEN * STYLE + col0;
#pragma unroll
    for (int nt = 0; nt < 4; ++nt) {
        const int c = nt * 16 + ln16;
        const float bs = bias[c];
#pragma unroll
        for (int i = 0; i < 4; ++i) {
            const int r = wv * 16 + qd * 4 + i;
            if (r < nrows) {
                const int orow = rows[r];
                out[(size_t)orow * STYLE + col0 + c] = 1.f / (1.f + __expf(-(acc[nt][i] + bs)));
            }
        }
    }
}

// ---------- fallback (ws too small): fused per-row, slow but correct ----------
__launch_bounds__(256)
__global__ void k_naive(const float* __restrict__ x, const int* __restrict__ m,
                        const float* __restrict__ fc1t, const float* __restrict__ fc2t,
                        float* __restrict__ out) {
    __shared__ float xs[IN_DIM];
    __shared__ float h1[HIDDEN];
    const int b = blockIdx.x, tid = threadIdx.x, L = m[b];
    for (int k = tid; k < IN_DIM; k += 256) xs[k] = x[(size_t)b * IN_DIM + k];
    __syncthreads();
    const float* __restrict__ W1 = fc1t + (size_t)L * FC1_STRIDE;
    for (int j = tid; j < HIDDEN; j += 256) {
        float acc = W1[(size_t)IN_DIM * HIDDEN + j];
        for (int k = 0; k < IN_DIM; ++k) acc = fmaf(xs[k], W1[(size_t)k * HIDDEN + j], acc);
        h1[j] = fmaxf(acc, 0.f);
    }
    __syncthreads();
    const float* __restrict__ W2 = fc2t + (size_t)L * FC2_STRIDE;
    for (int j = tid; j < STYLE; j += 256) {
        float acc = W2[(size_t)HIDDEN * STYLE + j];
        for (int k = 0; k < HIDDEN; ++k) acc = fmaf(h1[k], W2[(size_t)k * STYLE + j], acc);
        out[(size_t)b * STYLE + j] = 1.f / (1.f + __expf(-acc));
    }
}

extern "C" void kernel_launch(void* const* d_in, const int* in_sizes, int n_in,
                              void* d_out, int out_size, void* d_ws, size_t ws_size,
                              hipStream_t stream) {
    const float* x    = (const float*)d_in[0];
    const int*   m    = (const int*)d_in[1];
    const float* fc1t = (const float*)d_in[2];
    const float* fc2t = (const float*)d_in[3];
    float* out = (float*)d_out;

    if (ws_size >= BF16_NEED) {
        int*    meta = (int*)d_ws;
        ushort* w1b  = (ushort*)((char*)d_ws + W1B_OFF);
        ushort* w2b  = (ushort*)((char*)d_ws + W2B_OFF);
        ushort* h1b  = (ushort*)((char*)d_ws + H1B_OFF);

        k_prep<<<1 + W1_BLOCKS + W2_BLOCKS, 256, 0, stream>>>(m, fc1t, fc2t, meta, w1b, w2b);
        k_fc1m<<<dim3(MAX_TILES, HIDDEN / 64), 256, 0, stream>>>(x, w1b, fc1t, meta, h1b);
        k_fc2m<<<dim3(MAX_TILES, STYLE / 64), 256, 0, stream>>>(h1b, w2b, fc2t, meta, out);
    } else {
        k_naive<<<BATCH, 256, 0, stream>>>(x, m, fc1t, fc2t, out);
    }
}